// Round 13
// baseline (187.553 us; speedup 1.0000x reference)
//
#include <hip/hip_runtime.h>

#define M_HALF 16384
#define D 128
#define C 64
#define NBLK 256
#define NTHR 256
#define A_BLOCKS 64
#define A_ROWS 256
#define K3_ROWS 64

// 2 nodes: memset(ws header) + this kernel.
// Phase A (blocks 0..63): ballot-gather 256 rows -> atomic merge into protoSum.
// One load-polling grid barrier. Phase C (all 256): distances + loss.
__global__ __launch_bounds__(NTHR) void fused_proto_loss(
    const float* __restrict__ x, const int* __restrict__ y,
    int*   __restrict__ syncCnt,    // zeroed by memset
    float* __restrict__ protoSum,   // [4][C][32] = 8192 f, zeroed by memset
    float* __restrict__ cntSum,     // [C], zeroed by memset
    float* __restrict__ out)
{
    __shared__ float4 pT4[32 * 64];     // 32 KB
    __shared__ float  rc_s[C];
    __shared__ float  wsum[4];

    const int tid  = threadIdx.x;
    const int lane = tid & 63;
    const int blk  = blockIdx.x;

    // ---------------- Phase A: gather + atomic merge (blocks 0..63) --------
    if (blk < A_BLOCKS) {
        const int kq   = tid >> 6;               // wave id = k-quarter
        const int base = blk * A_ROWS;

        int yq[4];
        #pragma unroll
        for (int q = 0; q < 4; ++q) yq[q] = y[base + q * 64 + lane];

        unsigned long long msk[4] = {0ULL, 0ULL, 0ULL, 0ULL};
        for (int ci = 0; ci < C; ++ci) {
            #pragma unroll
            for (int q = 0; q < 4; ++q) {
                const unsigned long long b = __ballot(yq[q] == ci);
                if (lane == ci) msk[q] = b;
            }
        }

        if (kq == 0) {                           // counts: exact ints
            const int cnt = __popcll(msk[0]) + __popcll(msk[1]) +
                            __popcll(msk[2]) + __popcll(msk[3]);
            if (cnt) atomicAdd(&cntSum[lane], (float)cnt);
        }

        float acc[32];
        #pragma unroll
        for (int j = 0; j < 32; ++j) acc[j] = 0.f;
        #pragma unroll
        for (int q = 0; q < 4; ++q) {
            unsigned long long m = msk[q];
            while (m) {
                const int r = (int)__builtin_ctzll(m);
                m &= m - 1;
                const float4* xr =
                    (const float4*)(x + (size_t)(base + q * 64 + r) * D + kq * 32);
                #pragma unroll
                for (int j4 = 0; j4 < 8; ++j4) {
                    const float4 v = xr[j4];
                    acc[j4*4+0] += v.x; acc[j4*4+1] += v.y;
                    acc[j4*4+2] += v.z; acc[j4*4+3] += v.w;
                }
            }
        }

        float* dst = protoSum + (kq * 64 + lane) * 32;   // k = kq*32 + j
        #pragma unroll
        for (int j = 0; j < 32; ++j) atomicAdd(&dst[j], acc[j]);

        if (blk == 0 && tid == 0) out[0] = 0.f;  // before any phase-C atomicAdd
    }

    // ---------------- grid barrier: arrive=RMW once, poll=LOADs ------------
    __syncthreads();
    if (tid == 0) {
        __threadfence();                         // release protoSum/cntSum/out
        atomicAdd(syncCnt, 1);
        int guard = 0;
        while (__hip_atomic_load(syncCnt, __ATOMIC_ACQUIRE,
                                 __HIP_MEMORY_SCOPE_AGENT) < NBLK &&
               guard < (1 << 22)) {
            __builtin_amdgcn_s_sleep(8);
            ++guard;
        }
        __threadfence();                         // acquire
    }
    __syncthreads();

    // ---------------- Phase C: finalize pT, distances, logsumexp, loss -----
    if (tid < C) {
        float s = cntSum[tid];
        if (s < 0.5f) s = 1.f;                   // class_counts + (counts<0.01)
        rc_s[tid] = 1.f / s;
    }
    __syncthreads();

    for (int o = tid; o < 32 * 64; o += NTHR) {  // [k4][cc][cg] table
        const int k4 = o >> 6, cc = (o >> 4) & 3, cg = o & 15;
        const int c  = cg * 4 + cc;
        const int k0 = k4 * 4;
        const float4 v = *(const float4*)&protoSum[((k0 >> 5) * 64 + c) * 32 + (k0 & 31)];
        const float rc = rc_s[c];
        pT4[o] = make_float4(v.x * rc, v.y * rc, v.z * rc, v.w * rc);
    }
    __syncthreads();

    const int wid  = tid >> 6;
    const int cg   = lane & 15;      // classes 4*cg + cc
    const int rg   = lane >> 4;      // row group within wave
    const int rbase = wid * 16 + rg * 4;   // wave: 16 rows; thread: 4 rows
    const int row0 = M_HALF + blk * K3_ROWS;

    const float4* xrow[4];
    #pragma unroll
    for (int r = 0; r < 4; ++r)
        xrow[r] = (const float4*)(x + (size_t)(row0 + rbase + r) * D);

    float acc[4][4];
    #pragma unroll
    for (int r = 0; r < 4; ++r)
        #pragma unroll
        for (int cc = 0; cc < 4; ++cc) acc[r][cc] = 0.f;

    #pragma unroll 2
    for (int k4 = 0; k4 < 32; ++k4) {
        float4 pv[4], xv[4];
        #pragma unroll
        for (int cc = 0; cc < 4; ++cc) pv[cc] = pT4[k4 * 64 + cc * 16 + cg];
        #pragma unroll
        for (int r = 0; r < 4; ++r) xv[r] = xrow[r][k4];   // 16-lane broadcast
        #pragma unroll
        for (int r = 0; r < 4; ++r) {
            #pragma unroll
            for (int cc = 0; cc < 4; ++cc) {
                float d;
                d = xv[r].x - pv[cc].x; acc[r][cc] = fmaf(d, fabsf(d), acc[r][cc]);
                d = xv[r].y - pv[cc].y; acc[r][cc] = fmaf(d, fabsf(d), acc[r][cc]);
                d = xv[r].z - pv[cc].z; acc[r][cc] = fmaf(d, fabsf(d), acc[r][cc]);
                d = xv[r].w - pv[cc].w; acc[r][cc] = fmaf(d, fabsf(d), acc[r][cc]);
            }
        }
    }

    const float ninv_d = -1.f / (float)D;
    float lsum = 0.f;
    #pragma unroll
    for (int r = 0; r < 4; ++r) {
        float dv0 = acc[r][0] * ninv_d, dv1 = acc[r][1] * ninv_d;
        float dv2 = acc[r][2] * ninv_d, dv3 = acc[r][3] * ninv_d;
        float mx = fmaxf(fmaxf(dv0, dv1), fmaxf(dv2, dv3));
        #pragma unroll
        for (int off = 8; off; off >>= 1) mx = fmaxf(mx, __shfl_xor(mx, off));
        float se = __expf(dv0 - mx) + __expf(dv1 - mx) +
                   __expf(dv2 - mx) + __expf(dv3 - mx);
        #pragma unroll
        for (int off = 8; off; off >>= 1) se += __shfl_xor(se, off);
        const float lse = mx + __logf(se);

        const int yt  = y[row0 + rbase + r];     // uniform within 16-lane group
        const int cct = yt & 3, cgt = yt >> 2;   // class c = 4*cg + cc
        const float v01 = (cct & 1) ? dv1 : dv0;
        const float v23 = (cct & 1) ? dv3 : dv2;
        const float val = (cct & 2) ? v23 : v01;
        const float dy  = __shfl(val, (lane & 48) | cgt);
        lsum += lse - dy;                        // -logp[y]
    }

    lsum += __shfl_xor(lsum, 16);                // sum 4 rg-groups
    lsum += __shfl_xor(lsum, 32);

    if (lane == 0) wsum[wid] = lsum;
    __syncthreads();
    if (tid == 0) {
        const float tot = (wsum[0] + wsum[1] + wsum[2] + wsum[3]) * (1.f / (float)M_HALF);
        atomicAdd(out, tot);
    }
}

extern "C" void kernel_launch(void* const* d_in, const int* in_sizes, int n_in,
                              void* d_out, int out_size, void* d_ws, size_t ws_size,
                              hipStream_t stream) {
    const float* x = (const float*)d_in[0];   // [32768][128]
    const int*   y = (const int*)d_in[1];     // [32768]
    float* out = (float*)d_out;

    float* ws_f     = (float*)d_ws;
    int*   syncCnt  = (int*)ws_f;                        // ws_f[0]
    float* protoSum = ws_f + 16;                         // 8192 f, 64B-aligned
    float* cntSum   = protoSum + D * C;                  // 64 f

    // zero syncCnt + protoSum + cntSum in one contiguous memset
    hipMemsetAsync(ws_f, 0, (16 + D * C + C) * sizeof(float), stream);
    fused_proto_loss<<<NBLK, NTHR, 0, stream>>>(x, y, syncCnt, protoSum, cntSum, out);
}

// Round 14
// 40.642 us; speedup vs baseline: 4.6147x; 4.6147x over previous
//
#include <hip/hip_runtime.h>

#define M_HALF 16384
#define D 128
#define C 64

#define KP_BLOCKS 512            // block = (kq8 = blk>>6 in 0..7, class = blk&63)
#define KC_BLOCKS 256
#define KC_ROWS 64

// ---- K_P: direct prototype build; each block owns one (class, 16-float k-slice)
__global__ __launch_bounds__(256) void kp_proto(
    const float* __restrict__ x, const int* __restrict__ y,
    float* __restrict__ pTg,     // float idx: (k4*64 + cc*16 + cg)*4 + j
    float* __restrict__ out)
{
    __shared__ float red[4][16];
    __shared__ int   credw[4];
    const int tid  = threadIdx.x;
    const int lane = tid & 63;
    const int wid  = tid >> 6;
    const int blk  = blockIdx.x;
    const int myc  = blk & 63;
    const int kq8  = blk >> 6;           // 0..7 -> 16-float slice

    if (blk == 0 && tid == 0) out[0] = 0.f;   // before K_C's atomicAdd (kernel order)

    float acc[16];
    #pragma unroll
    for (int j = 0; j < 16; ++j) acc[j] = 0.f;
    int cnt = 0;

    const float* xbase = x + kq8 * 16;
    #pragma unroll 4
    for (int r = tid; r < M_HALF; r += 256) {   // y loads coalesced, L2-broadcast
        if (y[r] == myc) {
            ++cnt;
            const float4* xr = (const float4*)(xbase + (size_t)r * D);
            #pragma unroll
            for (int j4 = 0; j4 < 4; ++j4) {
                const float4 v = xr[j4];
                acc[j4*4+0] += v.x; acc[j4*4+1] += v.y;
                acc[j4*4+2] += v.z; acc[j4*4+3] += v.w;
            }
        }
    }

    // wave reduce (fixed order -> deterministic), then cross-wave via LDS
    #pragma unroll
    for (int off = 32; off; off >>= 1) {
        #pragma unroll
        for (int j = 0; j < 16; ++j) acc[j] += __shfl_xor(acc[j], off);
        cnt += __shfl_xor(cnt, off);
    }
    if (lane == 0) {
        #pragma unroll
        for (int j = 0; j < 16; ++j) red[wid][j] = acc[j];
        credw[wid] = cnt;
    }
    __syncthreads();
    if (tid < 16) {
        float tot = red[0][tid] + red[1][tid] + red[2][tid] + red[3][tid];
        float c = (float)(credw[0] + credw[1] + credw[2] + credw[3]);
        if (c < 0.5f) c = 1.f;           // class_counts + (counts < 0.01)
        tot /= c;
        const int k = kq8 * 16 + tid;
        pTg[((k >> 2) * 64 + (myc & 3) * 16 + (myc >> 2)) * 4 + (k & 3)] = tot;
    }
}

// ---- K_C: 4x4-register-tile distances + logsumexp + atomic loss (r11 K3 +
//          explicit xv register double-buffer to hide global-load latency) ----
__global__ __launch_bounds__(256) void kc_dist_loss(
    const float* __restrict__ x, const int* __restrict__ y,
    const float4* __restrict__ pTg4,    // [32][64] float4, finalized
    float* __restrict__ out)
{
    __shared__ float4 pT4[32 * 64];            // 32 KB, [k4][cc][cg]
    __shared__ float  wsum[4];
    const int tid = threadIdx.x;

    for (int o = tid; o < 32 * 64; o += 256) pT4[o] = pTg4[o];
    __syncthreads();

    const int lane = tid & 63;
    const int wid  = tid >> 6;
    const int cg   = lane & 15;      // classes 4*cg + cc
    const int rg   = lane >> 4;      // row group within wave
    const int rbase = wid * 16 + rg * 4;   // wave: 16 rows; thread: 4 rows
    const int row0 = M_HALF + blockIdx.x * KC_ROWS;

    const float4* xrow[4];
    #pragma unroll
    for (int r = 0; r < 4; ++r)
        xrow[r] = (const float4*)(x + (size_t)(row0 + rbase + r) * D);

    float acc[4][4];
    #pragma unroll
    for (int r = 0; r < 4; ++r)
        #pragma unroll
        for (int cc = 0; cc < 4; ++cc) acc[r][cc] = 0.f;

    float4 xv[4], xvn[4];
    #pragma unroll
    for (int r = 0; r < 4; ++r) xv[r] = xrow[r][0];   // prologue

    #pragma unroll 4
    for (int k4 = 0; k4 < 32; ++k4) {
        if (k4 < 31) {
            #pragma unroll
            for (int r = 0; r < 4; ++r) xvn[r] = xrow[r][k4 + 1];  // prefetch
        }
        float4 pv[4];
        #pragma unroll
        for (int cc = 0; cc < 4; ++cc) pv[cc] = pT4[k4 * 64 + cc * 16 + cg];
        #pragma unroll
        for (int r = 0; r < 4; ++r) {
            #pragma unroll
            for (int cc = 0; cc < 4; ++cc) {
                float d;
                d = xv[r].x - pv[cc].x; acc[r][cc] = fmaf(d, fabsf(d), acc[r][cc]);
                d = xv[r].y - pv[cc].y; acc[r][cc] = fmaf(d, fabsf(d), acc[r][cc]);
                d = xv[r].z - pv[cc].z; acc[r][cc] = fmaf(d, fabsf(d), acc[r][cc]);
                d = xv[r].w - pv[cc].w; acc[r][cc] = fmaf(d, fabsf(d), acc[r][cc]);
            }
        }
        #pragma unroll
        for (int r = 0; r < 4; ++r) xv[r] = xvn[r];
    }

    const float ninv_d = -1.f / (float)D;
    float lsum = 0.f;
    #pragma unroll
    for (int r = 0; r < 4; ++r) {
        float dv0 = acc[r][0] * ninv_d, dv1 = acc[r][1] * ninv_d;
        float dv2 = acc[r][2] * ninv_d, dv3 = acc[r][3] * ninv_d;
        float mx = fmaxf(fmaxf(dv0, dv1), fmaxf(dv2, dv3));
        #pragma unroll
        for (int off = 8; off; off >>= 1) mx = fmaxf(mx, __shfl_xor(mx, off));
        float se = __expf(dv0 - mx) + __expf(dv1 - mx) +
                   __expf(dv2 - mx) + __expf(dv3 - mx);
        #pragma unroll
        for (int off = 8; off; off >>= 1) se += __shfl_xor(se, off);
        const float lse = mx + __logf(se);

        const int yt  = y[row0 + rbase + r];     // uniform within 16-lane group
        const int cct = yt & 3, cgt = yt >> 2;   // class c = 4*cg + cc
        const float v01 = (cct & 1) ? dv1 : dv0;
        const float v23 = (cct & 1) ? dv3 : dv2;
        const float val = (cct & 2) ? v23 : v01;
        const float dy  = __shfl(val, (lane & 48) | cgt);
        lsum += lse - dy;                        // -logp[y]
    }

    lsum += __shfl_xor(lsum, 16);                // sum 4 rg-groups
    lsum += __shfl_xor(lsum, 32);

    if (lane == 0) wsum[wid] = lsum;
    __syncthreads();
    if (tid == 0) {
        const float tot = (wsum[0] + wsum[1] + wsum[2] + wsum[3]) * (1.f / (float)M_HALF);
        atomicAdd(out, tot);
    }
}

extern "C" void kernel_launch(void* const* d_in, const int* in_sizes, int n_in,
                              void* d_out, int out_size, void* d_ws, size_t ws_size,
                              hipStream_t stream) {
    const float* x = (const float*)d_in[0];   // [32768][128]
    const int*   y = (const int*)d_in[1];     // [32768]
    float* out = (float*)d_out;

    float* pTg = (float*)d_ws;                // 8192 floats

    kp_proto<<<KP_BLOCKS, 256, 0, stream>>>(x, y, pTg, out);
    kc_dist_loss<<<KC_BLOCKS, 256, 0, stream>>>(x, y, (const float4*)pTg, out);
}

// Round 15
// 36.264 us; speedup vs baseline: 5.1719x; 1.1207x over previous
//
#include <hip/hip_runtime.h>

#define M_HALF 16384
#define D 128
#define C 64

#define KP_BLOCKS 512            // block = (kq8 = blk>>6 in 0..7, class = blk&63)
#define KC_BLOCKS 256
#define KC_ROWS 64

// ---- K_P: direct prototype build; each block owns one (class, 16-float k-slice)
// Batched y-scan: 2 rounds x 8 independent int4 loads -> no 64-deep load chain.
__global__ __launch_bounds__(256) void kp_proto(
    const float* __restrict__ x, const int* __restrict__ y,
    float* __restrict__ pTg,     // float idx: (k4*64 + cc*16 + cg)*4 + j
    float* __restrict__ out)
{
    __shared__ float red[4][16];
    __shared__ int   credw[4];
    const int tid  = threadIdx.x;
    const int lane = tid & 63;
    const int wid  = tid >> 6;
    const int blk  = blockIdx.x;
    const int myc  = blk & 63;
    const int kq8  = blk >> 6;           // 0..7 -> 16-float slice

    if (blk == 0 && tid == 0) out[0] = 0.f;   // before K_C's atomicAdd

    float acc[16];
    #pragma unroll
    for (int j = 0; j < 16; ++j) acc[j] = 0.f;
    int cnt = 0;

    const float* xb = x + kq8 * 16;
    const int4* y4 = (const int4*)y;

    #pragma unroll
    for (int half = 0; half < 2; ++half) {
        int4 yv[8];
        #pragma unroll
        for (int i = 0; i < 8; ++i)                  // 8 independent int4 loads
            yv[i] = y4[(half * 8 + i) * 256 + tid];  // coalesced across threads
        #pragma unroll
        for (int i = 0; i < 8; ++i) {
            const int r0 = ((half * 8 + i) * 256 + tid) * 4;
            const int4 v = yv[i];
            #pragma unroll
            for (int s = 0; s < 4; ++s) {
                const int yl = (s == 0) ? v.x : (s == 1) ? v.y : (s == 2) ? v.z : v.w;
                if (yl == myc) {
                    ++cnt;
                    const float4* xr = (const float4*)(xb + (size_t)(r0 + s) * D);
                    #pragma unroll
                    for (int j4 = 0; j4 < 4; ++j4) {
                        const float4 vv = xr[j4];
                        acc[j4*4+0] += vv.x; acc[j4*4+1] += vv.y;
                        acc[j4*4+2] += vv.z; acc[j4*4+3] += vv.w;
                    }
                }
            }
        }
    }

    // wave reduce (fixed order -> deterministic), then cross-wave via LDS
    #pragma unroll
    for (int off = 32; off; off >>= 1) {
        #pragma unroll
        for (int j = 0; j < 16; ++j) acc[j] += __shfl_xor(acc[j], off);
        cnt += __shfl_xor(cnt, off);
    }
    if (lane == 0) {
        #pragma unroll
        for (int j = 0; j < 16; ++j) red[wid][j] = acc[j];
        credw[wid] = cnt;
    }
    __syncthreads();
    if (tid < 16) {
        float tot = red[0][tid] + red[1][tid] + red[2][tid] + red[3][tid];
        float c = (float)(credw[0] + credw[1] + credw[2] + credw[3]);
        if (c < 0.5f) c = 1.f;           // class_counts + (counts < 0.01)
        tot /= c;
        const int k = kq8 * 16 + tid;
        pTg[((k >> 2) * 64 + (myc & 3) * 16 + (myc >> 2)) * 4 + (k & 3)] = tot;
    }
}

// ---- K_C: 4x4-register-tile distances + logsumexp + atomic loss -----------
__global__ __launch_bounds__(256) void kc_dist_loss(
    const float* __restrict__ x, const int* __restrict__ y,
    const float4* __restrict__ pTg4,    // [32][64] float4, finalized
    float* __restrict__ out)
{
    __shared__ float4 pT4[32 * 64];            // 32 KB, [k4][cc][cg]
    __shared__ float  wsum[4];
    const int tid = threadIdx.x;

    for (int o = tid; o < 32 * 64; o += 256) pT4[o] = pTg4[o];
    __syncthreads();

    const int lane = tid & 63;
    const int wid  = tid >> 6;
    const int cg   = lane & 15;      // classes 4*cg + cc
    const int rg   = lane >> 4;      // row group within wave
    const int rbase = wid * 16 + rg * 4;   // wave: 16 rows; thread: 4 rows
    const int row0 = M_HALF + blockIdx.x * KC_ROWS;

    const float4* xrow[4];
    #pragma unroll
    for (int r = 0; r < 4; ++r)
        xrow[r] = (const float4*)(x + (size_t)(row0 + rbase + r) * D);

    float acc[4][4];
    #pragma unroll
    for (int r = 0; r < 4; ++r)
        #pragma unroll
        for (int cc = 0; cc < 4; ++cc) acc[r][cc] = 0.f;

    float4 xv[4], xvn[4];
    #pragma unroll
    for (int r = 0; r < 4; ++r) xv[r] = xrow[r][0];   // prologue

    #pragma unroll 4
    for (int k4 = 0; k4 < 32; ++k4) {
        if (k4 < 31) {
            #pragma unroll
            for (int r = 0; r < 4; ++r) xvn[r] = xrow[r][k4 + 1];  // prefetch
        }
        float4 pv[4];
        #pragma unroll
        for (int cc = 0; cc < 4; ++cc) pv[cc] = pT4[k4 * 64 + cc * 16 + cg];
        #pragma unroll
        for (int r = 0; r < 4; ++r) {
            #pragma unroll
            for (int cc = 0; cc < 4; ++cc) {
                float d;
                d = xv[r].x - pv[cc].x; acc[r][cc] = fmaf(d, fabsf(d), acc[r][cc]);
                d = xv[r].y - pv[cc].y; acc[r][cc] = fmaf(d, fabsf(d), acc[r][cc]);
                d = xv[r].z - pv[cc].z; acc[r][cc] = fmaf(d, fabsf(d), acc[r][cc]);
                d = xv[r].w - pv[cc].w; acc[r][cc] = fmaf(d, fabsf(d), acc[r][cc]);
            }
        }
        #pragma unroll
        for (int r = 0; r < 4; ++r) xv[r] = xvn[r];
    }

    const float ninv_d = -1.f / (float)D;
    float lsum = 0.f;
    #pragma unroll
    for (int r = 0; r < 4; ++r) {
        float dv0 = acc[r][0] * ninv_d, dv1 = acc[r][1] * ninv_d;
        float dv2 = acc[r][2] * ninv_d, dv3 = acc[r][3] * ninv_d;
        float mx = fmaxf(fmaxf(dv0, dv1), fmaxf(dv2, dv3));
        #pragma unroll
        for (int off = 8; off; off >>= 1) mx = fmaxf(mx, __shfl_xor(mx, off));
        float se = __expf(dv0 - mx) + __expf(dv1 - mx) +
                   __expf(dv2 - mx) + __expf(dv3 - mx);
        #pragma unroll
        for (int off = 8; off; off >>= 1) se += __shfl_xor(se, off);
        const float lse = mx + __logf(se);

        const int yt  = y[row0 + rbase + r];     // uniform within 16-lane group
        const int cct = yt & 3, cgt = yt >> 2;   // class c = 4*cg + cc
        const float v01 = (cct & 1) ? dv1 : dv0;
        const float v23 = (cct & 1) ? dv3 : dv2;
        const float val = (cct & 2) ? v23 : v01;
        const float dy  = __shfl(val, (lane & 48) | cgt);
        lsum += lse - dy;                        // -logp[y]
    }

    lsum += __shfl_xor(lsum, 16);                // sum 4 rg-groups
    lsum += __shfl_xor(lsum, 32);

    if (lane == 0) wsum[wid] = lsum;
    __syncthreads();
    if (tid == 0) {
        const float tot = (wsum[0] + wsum[1] + wsum[2] + wsum[3]) * (1.f / (float)M_HALF);
        atomicAdd(out, tot);
    }
}

extern "C" void kernel_launch(void* const* d_in, const int* in_sizes, int n_in,
                              void* d_out, int out_size, void* d_ws, size_t ws_size,
                              hipStream_t stream) {
    const float* x = (const float*)d_in[0];   // [32768][128]
    const int*   y = (const int*)d_in[1];     // [32768]
    float* out = (float*)d_out;

    float* pTg = (float*)d_ws;                // 8192 floats

    kp_proto<<<KP_BLOCKS, 256, 0, stream>>>(x, y, pTg, out);
    kc_dist_loss<<<KC_BLOCKS, 256, 0, stream>>>(x, y, (const float4*)pTg, out);
}